// Round 3
// baseline (156.801 us; speedup 1.0000x reference)
//
#include <hip/hip_runtime.h>

#define H_ 200
#define W_ 200
#define DELX_ 1.5f
#define DELY_ 1.5f
#define NXV_ 256
#define NYV_ 256
#define NZV_ 256
#define EPS_ 1e-8f
#define NSEG 16
#define PPB 16            // pixels per block (block = PPB * NSEG = 256 threads)

// alpha for integer plane k, via multiply by precomputed reciprocal (no divide)
__device__ __forceinline__ float alpha_mul(float k, float sp, float src, float inv_sdd) {
    return (k * sp - src) * inv_sdd;
}

__global__ void __launch_bounds__(256)
drr_fused(const float* __restrict__ vol,
          const float* __restrict__ spacing,
          const float* __restrict__ sdr,
          const float* __restrict__ rot,
          const float* __restrict__ trans,
          float* __restrict__ out,
          int B) {
    const int npix = B * H_ * W_;
    const int t = threadIdx.x;
    const int pixLocal = t & (PPB - 1);
    const int seg = t >> 4;                  // 0..15
    const int pix = blockIdx.x * PPB + pixLocal;
    const bool active = pix < npix;

    float result = 0.0f;
    if (active) {
        const int b = pix / (H_ * W_);
        const int p = pix % (H_ * W_);
        const int i = p / W_, j = p % W_;

        // --- rotation matrix R = Rz(theta) Ry(phi) Rx(gamma) ---
        const float theta = rot[b * 3 + 0], phi = rot[b * 3 + 1], gamma = rot[b * 3 + 2];
        const float ct = cosf(theta), st = sinf(theta);
        const float cp = cosf(phi),   sp = sinf(phi);
        const float cg = cosf(gamma), sg = sinf(gamma);
        const float r00 = ct * cp,                r10 = st * cp,                r20 = -sp;
        const float r01 = ct * sp * sg - st * cg, r11 = st * sp * sg + ct * cg, r21 = cp * sg;
        const float r02 = ct * sp * cg + st * sg, r12 = st * sp * cg - ct * sg, r22 = cp * cg;

        const float sd = sdr[b];
        const float tx = trans[b * 3 + 0], ty = trans[b * 3 + 1], tz = trans[b * 3 + 2];
        const float sx = sd * r00 + tx, sy = sd * r10 + ty, sz = sd * r20 + tz;
        const float cxx = -sd * r00 + tx, cyy = -sd * r10 + ty, czz = -sd * r20 + tz;

        const float tco = ((float)(i - H_ / 2) + 1.0f) * DELX_;
        const float sco = ((float)(j - W_ / 2) + 1.0f) * DELY_;
        const float gx = r01 * tco + r02 * sco + cxx;
        const float gy = r11 * tco + r12 * sco + cyy;
        const float gz = r21 * tco + r22 * sco + czz;

        const float dx = gx - sx + EPS_;
        const float dy = gy - sy + EPS_;
        const float dz = gz - sz + EPS_;

        const float spx = spacing[0], spy = spacing[1], spz = spacing[2];
        const float inv_spx = 1.0f / spx, inv_spy = 1.0f / spy, inv_spz = 1.0f / spz;
        const float inv_dx = 1.0f / dx, inv_dy = 1.0f / dy, inv_dz = 1.0f / dz;

        const float a0x = alpha_mul(0.f, spx, sx, inv_dx), a1x = alpha_mul((float)NXV_, spx, sx, inv_dx);
        const float a0y = alpha_mul(0.f, spy, sy, inv_dy), a1y = alpha_mul((float)NYV_, spy, sy, inv_dy);
        const float a0z = alpha_mul(0.f, spz, sz, inv_dz), a1z = alpha_mul((float)NZV_, spz, sz, inv_dz);

        const float amin = fmaxf(fmaxf(fminf(a0x, a1x), fminf(a0y, a1y)), fminf(a0z, a1z));
        const float amax = fminf(fminf(fmaxf(a0x, a1x), fmaxf(a0y, a1y)), fmaxf(a0z, a1z));

        const float norm = sqrtf(dx * dx + dy * dy + dz * dz);

        // segment bounds at x-plane crossings (exact members of the crossing set;
        // identical formula across segments -> bitwise-consistent partition)
        const float klo = (float)(seg * (NXV_ / NSEG));
        const float khi = (float)((seg + 1) * (NXV_ / NSEG));
        const float aA = alpha_mul(klo, spx, sx, inv_dx);
        const float aB = alpha_mul(khi, spx, sx, inv_dx);
        const float lo = fminf(aA, aB), hi = fmaxf(aA, aB);

        const float start = fmaxf(amin, lo);
        const float end   = fminf(amax, hi);

        float acc = 0.0f;
        if (start < end) {
            float kx, ky, kz, axv, ayv, azv, dkx, dky, dkz;
            {
                float kf = (start * dx + sx) * inv_spx;
                if (dx > 0.f) { dkx = 1.f;  kx = floorf(kf) + 1.f; }
                else          { dkx = -1.f; kx = ceilf(kf) - 1.f; }
                axv = alpha_mul(kx, spx, sx, inv_dx);
            }
            {
                float kf = (start * dy + sy) * inv_spy;
                if (dy > 0.f) { dky = 1.f;  ky = floorf(kf) + 1.f; }
                else          { dky = -1.f; ky = ceilf(kf) - 1.f; }
                ayv = alpha_mul(ky, spy, sy, inv_dy);
            }
            {
                float kf = (start * dz + sz) * inv_spz;
                if (dz > 0.f) { dkz = 1.f;  kz = floorf(kf) + 1.f; }
                else          { dkz = -1.f; kz = ceilf(kf) - 1.f; }
                azv = alpha_mul(kz, spz, sz, inv_dz);
            }

            float a_cur = start;
            int it = 0;
            while (it++ < 160) {
                float an = fminf(axv, fminf(ayv, azv));
                if (an > end) break;
                float stp = an - a_cur;
                float midv = 0.5f * (a_cur + an);
                float x = (sx + midv * dx) * inv_spx;
                float y = (sy + midv * dy) * inv_spy;
                float z = (sz + midv * dz) * inv_spz;
                int ix = (int)x;   // trunc toward zero, matches jnp.trunc->int32
                int iy = (int)y;
                int iz = (int)z;
                ix = min(max(ix, 0), NXV_ - 1);
                iy = min(max(iy, 0), NYV_ - 1);
                iz = min(max(iz, 0), NZV_ - 1);
                float v = vol[((NXV_ - 1 - ix) * NYV_ + iy) * NZV_ + iz];  // flip axis 0
                acc += v * stp;
                a_cur = an;
                if (axv == an) { kx += dkx; axv = alpha_mul(kx, spx, sx, inv_dx); }
                if (ayv == an) { ky += dky; ayv = alpha_mul(ky, spy, sy, inv_dy); }
                if (azv == an) { kz += dkz; azv = alpha_mul(kz, spz, sz, inv_dz); }
            }
        }
        result = acc * norm;
    }

    // block-level reduce: NSEG segments per pixel, fixed k-order summation
    __shared__ float red[NSEG * PPB];
    red[t] = result;
    __syncthreads();
    if (t < PPB && active) {
        float s = 0.0f;
        #pragma unroll
        for (int k = 0; k < NSEG; k++) s += red[t + k * PPB];
        out[pix] = s;
    }
}

extern "C" void kernel_launch(void* const* d_in, const int* in_sizes, int n_in,
                              void* d_out, int out_size, void* d_ws, size_t ws_size,
                              hipStream_t stream) {
    const float* vol     = (const float*)d_in[0];
    const float* spacing = (const float*)d_in[1];
    const float* sdr     = (const float*)d_in[2];
    const float* rot     = (const float*)d_in[3];
    const float* trans   = (const float*)d_in[4];
    float* out = (float*)d_out;

    const int B = in_sizes[2];
    const int npix = B * H_ * W_;
    const int nblocks = (npix + PPB - 1) / PPB;
    drr_fused<<<nblocks, NSEG * PPB, 0, stream>>>(vol, spacing, sdr, rot, trans, out, B);
}

// Round 4
// 126.079 us; speedup vs baseline: 1.2437x; 1.2437x over previous
//
#include <hip/hip_runtime.h>

#define H_ 200
#define W_ 200
#define DELX_ 1.5f
#define DELY_ 1.5f
#define NXV_ 256
#define NYV_ 256
#define NZV_ 256
#define EPS_ 1e-8f
#define NSEG 8
#define PPB 32            // pixels per block (block = PPB * NSEG = 256 threads)
#define TILE_R 8          // detector tile rows  (8x4 = 32 pixels)
#define TILE_C 4
#define TILES_PER_IMG ((H_ / TILE_R) * (W_ / TILE_C))   // 25*50 = 1250

// alpha for integer plane k, via multiply by precomputed reciprocal (no divide)
__device__ __forceinline__ float alpha_mul(float k, float sp, float src, float inv_sdd) {
    return (k * sp - src) * inv_sdd;
}

__global__ void __launch_bounds__(256)
drr_fused(const float* __restrict__ vol,
          const float* __restrict__ spacing,
          const float* __restrict__ sdr,
          const float* __restrict__ rot,
          const float* __restrict__ trans,
          float* __restrict__ out) {
    const int t = threadIdx.x;
    const int pixLocal = t & (PPB - 1);     // 0..31
    const int seg = t >> 5;                 // 0..7 ; wave = 32 px x 2 adjacent segs

    // 2D detector tiling: 8x4 pixel patch per 32-pixel group
    const int b   = blockIdx.x / TILES_PER_IMG;
    const int rem = blockIdx.x % TILES_PER_IMG;
    const int ty  = rem / (W_ / TILE_C);
    const int tx  = rem % (W_ / TILE_C);
    const int i = ty * TILE_R + (pixLocal >> 2);
    const int j = tx * TILE_C + (pixLocal & 3);
    const int pix = b * (H_ * W_) + i * W_ + j;

    // --- rotation matrix R = Rz(theta) Ry(phi) Rx(gamma) ---
    const float theta = rot[b * 3 + 0], phi = rot[b * 3 + 1], gamma = rot[b * 3 + 2];
    const float ct = cosf(theta), st = sinf(theta);
    const float cp = cosf(phi),   sp = sinf(phi);
    const float cg = cosf(gamma), sg = sinf(gamma);
    const float r00 = ct * cp,                r10 = st * cp,                r20 = -sp;
    const float r01 = ct * sp * sg - st * cg, r11 = st * sp * sg + ct * cg, r21 = cp * sg;
    const float r02 = ct * sp * cg + st * sg, r12 = st * sp * cg - ct * sg, r22 = cp * cg;

    const float sd = sdr[b];
    const float tx_ = trans[b * 3 + 0], ty_ = trans[b * 3 + 1], tz_ = trans[b * 3 + 2];
    const float sx = sd * r00 + tx_, sy = sd * r10 + ty_, sz = sd * r20 + tz_;
    const float cxx = -sd * r00 + tx_, cyy = -sd * r10 + ty_, czz = -sd * r20 + tz_;

    const float tco = ((float)(i - H_ / 2) + 1.0f) * DELX_;
    const float sco = ((float)(j - W_ / 2) + 1.0f) * DELY_;
    const float gx = r01 * tco + r02 * sco + cxx;
    const float gy = r11 * tco + r12 * sco + cyy;
    const float gz = r21 * tco + r22 * sco + czz;

    const float dx = gx - sx + EPS_;
    const float dy = gy - sy + EPS_;
    const float dz = gz - sz + EPS_;

    const float spx = spacing[0], spy = spacing[1], spz = spacing[2];
    const float inv_spx = 1.0f / spx, inv_spy = 1.0f / spy, inv_spz = 1.0f / spz;
    const float inv_dx = 1.0f / dx, inv_dy = 1.0f / dy, inv_dz = 1.0f / dz;

    const float a0x = alpha_mul(0.f, spx, sx, inv_dx), a1x = alpha_mul((float)NXV_, spx, sx, inv_dx);
    const float a0y = alpha_mul(0.f, spy, sy, inv_dy), a1y = alpha_mul((float)NYV_, spy, sy, inv_dy);
    const float a0z = alpha_mul(0.f, spz, sz, inv_dz), a1z = alpha_mul((float)NZV_, spz, sz, inv_dz);

    const float amin = fmaxf(fmaxf(fminf(a0x, a1x), fminf(a0y, a1y)), fminf(a0z, a1z));
    const float amax = fminf(fminf(fmaxf(a0x, a1x), fmaxf(a0y, a1y)), fmaxf(a0z, a1z));

    const float norm = sqrtf(dx * dx + dy * dy + dz * dz);

    // segment bounds at x-plane crossings (exact members of the crossing set;
    // identical formula across segments -> bitwise-consistent partition)
    const float klo = (float)(seg * (NXV_ / NSEG));
    const float khi = (float)((seg + 1) * (NXV_ / NSEG));
    const float aA = alpha_mul(klo, spx, sx, inv_dx);
    const float aB = alpha_mul(khi, spx, sx, inv_dx);
    const float lo = fminf(aA, aB), hi = fmaxf(aA, aB);

    const float start = fmaxf(amin, lo);
    const float end   = fminf(amax, hi);

    float acc = 0.0f;
    if (start < end) {
        float kx, ky, kz, axv, ayv, azv, dkx, dky, dkz;
        {
            float kf = (start * dx + sx) * inv_spx;
            if (dx > 0.f) { dkx = 1.f;  kx = floorf(kf) + 1.f; }
            else          { dkx = -1.f; kx = ceilf(kf) - 1.f; }
            axv = alpha_mul(kx, spx, sx, inv_dx);
        }
        {
            float kf = (start * dy + sy) * inv_spy;
            if (dy > 0.f) { dky = 1.f;  ky = floorf(kf) + 1.f; }
            else          { dky = -1.f; ky = ceilf(kf) - 1.f; }
            ayv = alpha_mul(ky, spy, sy, inv_dy);
        }
        {
            float kf = (start * dz + sz) * inv_spz;
            if (dz > 0.f) { dkz = 1.f;  kz = floorf(kf) + 1.f; }
            else          { dkz = -1.f; kz = ceilf(kf) - 1.f; }
            azv = alpha_mul(kz, spz, sz, inv_dz);
        }

        float a_cur = start;
        // groups of 4 steps: march 4 (addresses+steps), then 4 loads in flight
        for (int g = 0; g < 40; ++g) {
            float stp[4];
            int   off[4];
            float an_last;
            #pragma unroll
            for (int u = 0; u < 4; ++u) {
                float an = fminf(axv, fminf(ayv, azv));
                bool ok = (an <= end);
                stp[u] = ok ? (an - a_cur) : 0.0f;
                float midv = 0.5f * (a_cur + an);
                float x = (sx + midv * dx) * inv_spx;
                float y = (sy + midv * dy) * inv_spy;
                float z = (sz + midv * dz) * inv_spz;
                int ix = (int)x;   // trunc toward zero, matches jnp.trunc->int32
                int iy = (int)y;
                int iz = (int)z;
                ix = min(max(ix, 0), NXV_ - 1);
                iy = min(max(iy, 0), NYV_ - 1);
                iz = min(max(iz, 0), NZV_ - 1);
                off[u] = ((NXV_ - 1 - ix) * NYV_ + iy) * NZV_ + iz;  // flip axis 0
                a_cur = an;
                bool cx = (axv == an), cy = (ayv == an), cz = (azv == an);
                kx = cx ? kx + dkx : kx;
                ky = cy ? ky + dky : ky;
                kz = cz ? kz + dkz : kz;
                axv = alpha_mul(kx, spx, sx, inv_dx);  // bitwise-stable recompute
                ayv = alpha_mul(ky, spy, sy, inv_dy);
                azv = alpha_mul(kz, spz, sz, inv_dz);
                an_last = an;
            }
            float v0 = vol[off[0]];
            float v1 = vol[off[1]];
            float v2 = vol[off[2]];
            float v3 = vol[off[3]];
            acc += v0 * stp[0];
            acc += v1 * stp[1];
            acc += v2 * stp[2];
            acc += v3 * stp[3];
            if (an_last > end) break;
        }
    }
    float result = acc * norm;

    // block-level reduce: NSEG segments per pixel, fixed k-order summation
    __shared__ float red[NSEG * PPB];
    red[t] = result;
    __syncthreads();
    if (t < PPB) {
        // recompute this thread's pixel (t == pixLocal here)
        const int ii = ty * TILE_R + (t >> 2);
        const int jj = tx * TILE_C + (t & 3);
        const int opix = b * (H_ * W_) + ii * W_ + jj;
        float s = 0.0f;
        #pragma unroll
        for (int k = 0; k < NSEG; k++) s += red[t + k * PPB];
        out[opix] = s;
    }
}

extern "C" void kernel_launch(void* const* d_in, const int* in_sizes, int n_in,
                              void* d_out, int out_size, void* d_ws, size_t ws_size,
                              hipStream_t stream) {
    const float* vol     = (const float*)d_in[0];
    const float* spacing = (const float*)d_in[1];
    const float* sdr     = (const float*)d_in[2];
    const float* rot     = (const float*)d_in[3];
    const float* trans   = (const float*)d_in[4];
    float* out = (float*)d_out;

    const int B = in_sizes[2];
    const int nblocks = B * TILES_PER_IMG;
    drr_fused<<<nblocks, NSEG * PPB, 0, stream>>>(vol, spacing, sdr, rot, trans, out);
}